// Round 11
// baseline (95.587 us; speedup 1.0000x reference)
//
#include <hip/hip_runtime.h>
#include <hip/hip_bf16.h>

#define C_DIM 128
#define H_DIM 32

typedef __attribute__((ext_vector_type(8))) short bf16x8;
typedef __attribute__((ext_vector_type(4))) float f32x4;

// fast tanh: tanh(x) = 1 - 2/(e^{2x}+1). Handles +-inf correctly.
__device__ __forceinline__ float tanh_fast(float x) {
    float e = __expf(2.0f * x);
    return 1.0f - 2.0f * __builtin_amdgcn_rcpf(e + 1.0f);
}

// f32 -> bf16 RNE via library cast (compiler emits v_cvt_pk_bf16_f32 pairs)
__device__ __forceinline__ short f2bf(float f) {
    return __builtin_bit_cast(short, __float2bfloat16(f));
}

// Chebyshev -> monomial: p(t) = e0 + e1 t + e2 t^2 + e3 t^3 + e4 t^4
//   e0 = c0 - c2 + c4; e1 = c1 - 3c3; e2 = 2c2 - 8c4; e3 = 4c3; e4 = 8c4
// e0 folded into bias1 (summed over channels).
// Layer-1 coeffs packed directly in MFMA B-fragment order (bf16); the
// A-builder uses the IDENTICAL (lane,j)->(channel,power) map, so any hw
// k-permutation cancels (A/B fragment layouts are symmetric).
__global__ void prep_kernel(const float* __restrict__ c1, const float* __restrict__ c2,
                            unsigned short* __restrict__ Bpack, float* __restrict__ bias1,
                            float* __restrict__ E2, float* __restrict__ bias2) {
    const int tid = threadIdx.x;
    const int idx = blockIdx.x * 256 + tid;   // grid 64*256 = 16384 = one per element
    {
        int kc = idx >> 10;
        int oh = (idx >> 9) & 1;
        int l  = (idx >> 3) & 63;
        int j  = idx & 7;
        int g  = l >> 4;
        int kc2 = kc >> 1, kh = kc & 1;
        int c   = kc2 * 16 + 4 * g + 2 * kh + (j >> 2);
        int col = oh * 16 + (l & 15);
        int p   = j & 3;
        const float* cc = c1 + (c * H_DIM + col) * 5;
        float v = (p == 0) ? cc[1] - 3.0f * cc[3]
                : (p == 1) ? 2.0f * cc[2] - 8.0f * cc[4]
                : (p == 2) ? 4.0f * cc[3]
                           : 8.0f * cc[4];
        Bpack[idx] = (unsigned short)f2bf(v);
    }
    if (blockIdx.x == 0) {
        __shared__ float part[256];
        const int o = tid & 31, ch = tid >> 5;
        float b = 0.0f;
        for (int i = ch * 16; i < ch * 16 + 16; ++i) {
            const float* cc = c1 + (i * H_DIM + o) * 5;
            b += cc[0] - cc[2] + cc[4];
        }
        part[tid] = b;
        __syncthreads();
        if (tid < 32) {
            float s = 0.0f;
            #pragma unroll
            for (int k = 0; k < 8; ++k) s += part[k * 32 + tid];
            bias1[tid] = s;
            const float* cc = c2 + tid * 5;
            float4 e;
            e.x = cc[1] - 3.0f * cc[3];
            e.y = 2.0f * cc[2] - 8.0f * cc[4];
            e.z = 4.0f * cc[3];
            e.w = 8.0f * cc[4];
            reinterpret_cast<float4*>(E2)[tid] = e;
        }
        __syncthreads();
        if (tid < 32) part[tid] = c2[tid * 5] - c2[tid * 5 + 2] + c2[tid * 5 + 4];
        __syncthreads();
        if (tid == 0) {
            float b2 = 0.0f;
            for (int h = 0; h < 32; ++h) b2 += part[h];
            bias2[0] = b2;
        }
    }
}

// R11: ALL global accesses lane-contiguous.
//  - PR: block tile (128 rows x 512B = 64KB) staged linearly into LDS
//    (1KB contiguous per wave instr, m13 copy pattern), XOR-swizzled on the
//    write side (o ^= (row&7)<<4) so the K-loop's column-band ds_read_b128
//    is uniformly spread over all 32 banks (8 lanes x 8 slots = minimum
//    phases for a 1KB wave read).
//  - B-frags: read from global (32KB, L2-resident), lane-contiguous.
//  - scale: unioned into each wave's OWN already-consumed LDS rows.
// Tests (and exploits) the R4-R10 invariant: row-strided wave loads pinned
// at ~2.4 TB/s while lane-contiguous streams hit ~6-7 TB/s.
__global__ __launch_bounds__(256, 2) void fused_kernel(
        const float* __restrict__ PRV, const float* __restrict__ PR,
        const unsigned short* __restrict__ Bpack, const float* __restrict__ bias1,
        const float* __restrict__ E2, const float* __restrict__ bias2,
        const float* __restrict__ gamma, const float* __restrict__ beta,
        const float* __restrict__ alphap, float* __restrict__ out) {
    __shared__ char smem[65536];          // 64KB: swizzled PR tile, later scales
    float* sPRf = reinterpret_cast<float*>(smem);

    const int tid  = threadIdx.x;
    const int wid  = tid >> 6;
    const int lane = tid & 63;
    const int g    = lane >> 4;
    const int lr   = lane & 15;

    // ---- linear PR staging: 64KB contiguous per block, swizzled write ----
    const float4* prsrc = reinterpret_cast<const float4*>(PR) + (size_t)blockIdx.x * 4096;
    #pragma unroll
    for (int i = 0; i < 16; ++i) {
        int fi  = i * 256 + tid;          // float4 index in tile (0..4095)
        int row = fi >> 5;                // 32 float4 per row
        int ob  = ((fi & 31) * 16) ^ ((row & 7) << 4);
        *reinterpret_cast<float4*>(smem + row * 512 + ob) = prsrc[fi];
    }
    __syncthreads();

    // epilogue constants
    const float gam0 = gamma[lr], gam1 = gamma[16 + lr];
    const float bet0 = beta[lr],  bet1 = beta[16 + lr];
    const f32x4 e2a = reinterpret_cast<const f32x4*>(E2)[lr];
    const f32x4 e2b = reinterpret_cast<const f32x4*>(E2)[16 + lr];
    const float zb = bias2[0];
    const float alpha = alphap[0];

    f32x4 acc[2][2];
    {
        float b0 = bias1[lr], b1 = bias1[16 + lr];
        #pragma unroll
        for (int t = 0; t < 2; ++t) {
            acc[t][0] = (f32x4){b0, b0, b0, b0};
            acc[t][1] = (f32x4){b1, b1, b1, b1};
        }
    }

    const bf16x8* Bg = reinterpret_cast<const bf16x8*>(Bpack);   // L2-hot 32KB
    const int rA = wid * 32 + lr;         // local row, first M-tile
    const int rB = rA + 16;               // second M-tile ((+16) keeps row&7)
    const int swz = (lr & 7) << 4;

    // K-loop: 8 chunks of K=64; A from swizzled LDS, B from L2
    #pragma unroll
    for (int kc2 = 0; kc2 < 8; ++kc2) {
        const int o = kc2 * 64 + g * 16;
        f32x4 x0 = *reinterpret_cast<const f32x4*>(smem + rA * 512 + (o ^ swz));
        f32x4 x1 = *reinterpret_cast<const f32x4*>(smem + rB * 512 + (o ^ swz));
        bf16x8 be0 = Bg[(kc2 * 4 + 0) * 64 + lane];
        bf16x8 be1 = Bg[(kc2 * 4 + 1) * 64 + lane];
        bf16x8 bo0 = Bg[(kc2 * 4 + 2) * 64 + lane];
        bf16x8 bo1 = Bg[(kc2 * 4 + 3) * 64 + lane];
        #define DO_TILE(XC, T) { \
            float t0 = tanh_fast(XC[0]), t1 = tanh_fast(XC[1]); \
            float t2 = tanh_fast(XC[2]), t3 = tanh_fast(XC[3]); \
            float s0 = t0 * t0, s1 = t1 * t1, s2 = t2 * t2, s3 = t3 * t3; \
            bf16x8 ae, ao; \
            ae[0] = f2bf(t0); ae[1] = f2bf(s0); ae[2] = f2bf(s0 * t0); ae[3] = f2bf(s0 * s0); \
            ae[4] = f2bf(t1); ae[5] = f2bf(s1); ae[6] = f2bf(s1 * t1); ae[7] = f2bf(s1 * s1); \
            ao[0] = f2bf(t2); ao[1] = f2bf(s2); ao[2] = f2bf(s2 * t2); ao[3] = f2bf(s2 * s2); \
            ao[4] = f2bf(t3); ao[5] = f2bf(s3); ao[6] = f2bf(s3 * t3); ao[7] = f2bf(s3 * s3); \
            acc[T][0] = __builtin_amdgcn_mfma_f32_16x16x32_bf16(ae, be0, acc[T][0], 0, 0, 0); \
            acc[T][1] = __builtin_amdgcn_mfma_f32_16x16x32_bf16(ae, be1, acc[T][1], 0, 0, 0); \
            acc[T][0] = __builtin_amdgcn_mfma_f32_16x16x32_bf16(ao, bo0, acc[T][0], 0, 0, 0); \
            acc[T][1] = __builtin_amdgcn_mfma_f32_16x16x32_bf16(ao, bo1, acc[T][1], 0, 0, 0); }
        DO_TILE(x0, 0)
        DO_TILE(x1, 1)
        #undef DO_TILE
    }

    // ---- LayerNorm + ReLU + layer-2 ChebyKAN + sigmoid, per M-tile ----
    // C layout: col = oh*16 + lr, row = g*4 + reg  (verified m89/m91)
    #pragma unroll
    for (int t = 0; t < 2; ++t) {
        f32x4 a0 = acc[t][0], a1 = acc[t][1];
        float s[4], vs[4], z[4];
        #pragma unroll
        for (int r = 0; r < 4; ++r) s[r] = a0[r] + a1[r];
        #pragma unroll
        for (int m = 1; m <= 8; m <<= 1) {
            #pragma unroll
            for (int r = 0; r < 4; ++r) s[r] += __shfl_xor(s[r], m, 64);
        }
        #pragma unroll
        for (int r = 0; r < 4; ++r) {
            float mu = s[r] * (1.0f / 32.0f);
            float d0 = a0[r] - mu, d1 = a1[r] - mu;
            a0[r] = d0; a1[r] = d1;
            vs[r] = d0 * d0 + d1 * d1;
        }
        #pragma unroll
        for (int m = 1; m <= 8; m <<= 1) {
            #pragma unroll
            for (int r = 0; r < 4; ++r) vs[r] += __shfl_xor(vs[r], m, 64);
        }
        #pragma unroll
        for (int r = 0; r < 4; ++r) {
            float rs = rsqrtf(vs[r] * (1.0f / 32.0f) + 1e-5f);
            float h0 = fmaf(a0[r] * rs, gam0, bet0);
            float h1 = fmaf(a1[r] * rs, gam1, bet1);
            h0 = fmaxf(h0, 0.0f); h1 = fmaxf(h1, 0.0f);
            float t0 = tanh_fast(h0), t1 = tanh_fast(h1);
            float t02 = t0 * t0, t12 = t1 * t1;
            float zp = fmaf(e2a[0], t0, fmaf(e2a[1], t02,
                        fmaf(e2a[2], t02 * t0, e2a[3] * (t02 * t02))));
            zp += fmaf(e2b[0], t1, fmaf(e2b[1], t12,
                    fmaf(e2b[2], t12 * t1, e2b[3] * (t12 * t12))));
            z[r] = zp;
        }
        #pragma unroll
        for (int m = 1; m <= 8; m <<= 1) {
            #pragma unroll
            for (int r = 0; r < 4; ++r) z[r] += __shfl_xor(z[r], m, 64);
        }
        if (lr == 0) {
            // union: wave's scales land in its OWN rows' LDS (already consumed)
            #pragma unroll
            for (int r = 0; r < 4; ++r) {
                float attn = __builtin_amdgcn_rcpf(1.0f + __expf(-(z[r] + zb)));
                sPRf[wid * 4096 + t * 16 + g * 4 + r] = fmaf(alpha, attn, 1.0f);
            }
        }
    }
    __syncthreads();

    // ---- coalesced gate sweep: out = PRV * (1 + alpha*attn), 128 rows ----
    const size_t base = (size_t)blockIdx.x * 4096;
    const float4* prv4 = reinterpret_cast<const float4*>(PRV) + base;
    float4* out4 = reinterpret_cast<float4*>(out) + base;
    #pragma unroll 4
    for (int it = 0; it < 16; ++it) {
        int idx = it * 256 + tid;
        int R = idx >> 5;                      // local row 0..127
        float sc = sPRf[(R >> 5) * 4096 + (R & 31)];
        float4 v = prv4[idx];
        v.x *= sc; v.y *= sc; v.z *= sc; v.w *= sc;
        out4[idx] = v;
    }
}

extern "C" void kernel_launch(void* const* d_in, const int* in_sizes, int n_in,
                              void* d_out, int out_size, void* d_ws, size_t ws_size,
                              hipStream_t stream) {
    const float* PRV    = (const float*)d_in[0];
    const float* PR     = (const float*)d_in[1];
    const float* c1     = (const float*)d_in[2];
    const float* gamma  = (const float*)d_in[3];
    const float* beta   = (const float*)d_in[4];
    const float* c2     = (const float*)d_in[5];
    const float* alphap = (const float*)d_in[6];
    float* out = (float*)d_out;

    unsigned short* Bpack = (unsigned short*)d_ws;            // 32 KB bf16 frags
    float* wsf   = (float*)((char*)d_ws + 32768);
    float* bias1 = wsf;          // 32
    float* E2    = wsf + 32;     // 128 (32 x float4)
    float* bias2 = wsf + 160;    // 1

    const int N = in_sizes[0] / C_DIM;

    hipLaunchKernelGGL(prep_kernel, dim3(64), dim3(256), 0, stream,
                       c1, c2, Bpack, bias1, E2, bias2);
    hipLaunchKernelGGL(fused_kernel, dim3(N / 128), dim3(256), 0, stream,
                       PRV, PR, Bpack, bias1, E2, bias2, gamma, beta, alphap, out);
}

// Round 12
// 89.873 us; speedup vs baseline: 1.0636x; 1.0636x over previous
//
#include <hip/hip_runtime.h>
#include <hip/hip_bf16.h>

#define C_DIM 128
#define H_DIM 32

typedef __attribute__((ext_vector_type(8))) short bf16x8;
typedef __attribute__((ext_vector_type(4))) float f32x4;

// fast tanh: tanh(x) = 1 - 2/(e^{2x}+1). Handles +-inf correctly.
__device__ __forceinline__ float tanh_fast(float x) {
    float e = __expf(2.0f * x);
    return 1.0f - 2.0f * __builtin_amdgcn_rcpf(e + 1.0f);
}

// f32 -> bf16 RNE via library cast (compiler emits v_cvt_pk_bf16_f32 pairs)
__device__ __forceinline__ short f2bf(float f) {
    return __builtin_bit_cast(short, __float2bfloat16(f));
}

// Chebyshev -> monomial: p(t) = e0 + e1 t + e2 t^2 + e3 t^3 + e4 t^4
//   e0 = c0 - c2 + c4; e1 = c1 - 3c3; e2 = 2c2 - 8c4; e3 = 4c3; e4 = 8c4
// e0 folded into bias1 (summed over channels).
// Layer-1 coeffs packed directly in MFMA B-fragment order (bf16); the
// A-builder uses the IDENTICAL (lane,j)->(channel,power) map, so any hw
// k-permutation cancels (A/B fragment layouts are symmetric).
__global__ void prep_kernel(const float* __restrict__ c1, const float* __restrict__ c2,
                            unsigned short* __restrict__ Bpack, float* __restrict__ bias1,
                            float* __restrict__ E2, float* __restrict__ bias2) {
    const int tid = threadIdx.x;
    const int idx = blockIdx.x * 256 + tid;   // grid 64*256 = 16384 = one per element
    {
        int kc = idx >> 10;
        int oh = (idx >> 9) & 1;
        int l  = (idx >> 3) & 63;
        int j  = idx & 7;
        int g  = l >> 4;
        int kc2 = kc >> 1, kh = kc & 1;
        int c   = kc2 * 16 + 4 * g + 2 * kh + (j >> 2);
        int col = oh * 16 + (l & 15);
        int p   = j & 3;
        const float* cc = c1 + (c * H_DIM + col) * 5;
        float v = (p == 0) ? cc[1] - 3.0f * cc[3]
                : (p == 1) ? 2.0f * cc[2] - 8.0f * cc[4]
                : (p == 2) ? 4.0f * cc[3]
                           : 8.0f * cc[4];
        Bpack[idx] = (unsigned short)f2bf(v);
    }
    if (blockIdx.x == 0) {
        __shared__ float part[256];
        const int o = tid & 31, ch = tid >> 5;
        float b = 0.0f;
        for (int i = ch * 16; i < ch * 16 + 16; ++i) {
            const float* cc = c1 + (i * H_DIM + o) * 5;
            b += cc[0] - cc[2] + cc[4];
        }
        part[tid] = b;
        __syncthreads();
        if (tid < 32) {
            float s = 0.0f;
            #pragma unroll
            for (int k = 0; k < 8; ++k) s += part[k * 32 + tid];
            bias1[tid] = s;
            const float* cc = c2 + tid * 5;
            float4 e;
            e.x = cc[1] - 3.0f * cc[3];
            e.y = 2.0f * cc[2] - 8.0f * cc[4];
            e.z = 4.0f * cc[3];
            e.w = 8.0f * cc[4];
            reinterpret_cast<float4*>(E2)[tid] = e;
        }
        __syncthreads();
        if (tid < 32) part[tid] = c2[tid * 5] - c2[tid * 5 + 2] + c2[tid * 5 + 4];
        __syncthreads();
        if (tid == 0) {
            float b2 = 0.0f;
            for (int h = 0; h < 32; ++h) b2 += part[h];
            bias2[0] = b2;
        }
    }
}

// R12: fully wave-local pipeline, ZERO barriers.
// Each wave: stage own 16 rows (8KB, contiguous 1KB loads, swizzled LDS
// writes) -> K-loop (A: own LDS slice; B: lane-contiguous L2-hot global)
// -> epilogue (one 16x32 tile) -> own 16 scales into own LDS slice
// -> sweep own 16 rows (contiguous). 8 waves/block free-run and stagger
// phases naturally. LDS = 64KB -> 2 blocks/CU = 16 waves/CU; all global
// accesses lane-contiguous (R11 pattern fix, occupancy confound removed).
__global__ __launch_bounds__(512, 4) void fused_kernel(
        const float* __restrict__ PRV, const float* __restrict__ PR,
        const unsigned short* __restrict__ Bpack, const float* __restrict__ bias1,
        const float* __restrict__ E2, const float* __restrict__ bias2,
        const float* __restrict__ gamma, const float* __restrict__ beta,
        const float* __restrict__ alphap, float* __restrict__ out) {
    __shared__ char smem[65536];          // 8 waves x 8KB wave-local slices

    const int tid  = threadIdx.x;
    const int w    = tid >> 6;
    const int lane = tid & 63;
    const int g    = lane >> 4;
    const int lr   = lane & 15;
    char* ws = smem + (w << 13);          // this wave's 8KB slice

    // ---- stage own 16 rows: 8 x 1KB contiguous, swizzled LDS write ----
    const size_t rowbase = ((size_t)blockIdx.x * 128 + w * 16) * 32;  // float4 units
    const float4* prsrc = reinterpret_cast<const float4*>(PR) + rowbase;
    #pragma unroll
    for (int it = 0; it < 8; ++it) {
        int fi  = it * 64 + lane;         // 0..511
        int r16 = fi >> 5;                // row 0..15 (32 float4 per row)
        int ob  = ((fi & 31) * 16) ^ ((r16 & 7) << 4);
        *reinterpret_cast<float4*>(ws + r16 * 512 + ob) = prsrc[fi];
    }

    // epilogue constants (scalar/uniform loads)
    const float gam0 = gamma[lr], gam1 = gamma[16 + lr];
    const float bet0 = beta[lr],  bet1 = beta[16 + lr];
    const f32x4 e2a = reinterpret_cast<const f32x4*>(E2)[lr];
    const f32x4 e2b = reinterpret_cast<const f32x4*>(E2)[16 + lr];
    const float zb = bias2[0];
    const float alpha = alphap[0];

    f32x4 acc0, acc1;
    {
        float b0 = bias1[lr], b1 = bias1[16 + lr];
        acc0 = (f32x4){b0, b0, b0, b0};
        acc1 = (f32x4){b1, b1, b1, b1};
    }

    const bf16x8* Bg = reinterpret_cast<const bf16x8*>(Bpack);   // L2-hot 32KB
    const int swz = (lr & 7) << 4;

    // ---- K-loop: 8 chunks of K=64; A from own LDS, B from L2 ----
    #pragma unroll
    for (int kc2 = 0; kc2 < 8; ++kc2) {
        f32x4 x = *reinterpret_cast<const f32x4*>(
                      ws + lr * 512 + ((kc2 * 64 + g * 16) ^ swz));
        bf16x8 be0 = Bg[(kc2 * 4 + 0) * 64 + lane];
        bf16x8 be1 = Bg[(kc2 * 4 + 1) * 64 + lane];
        bf16x8 bo0 = Bg[(kc2 * 4 + 2) * 64 + lane];
        bf16x8 bo1 = Bg[(kc2 * 4 + 3) * 64 + lane];
        float t0 = tanh_fast(x[0]), t1 = tanh_fast(x[1]);
        float t2 = tanh_fast(x[2]), t3 = tanh_fast(x[3]);
        float s0 = t0 * t0, s1 = t1 * t1, s2 = t2 * t2, s3 = t3 * t3;
        bf16x8 ae, ao;
        ae[0] = f2bf(t0); ae[1] = f2bf(s0); ae[2] = f2bf(s0 * t0); ae[3] = f2bf(s0 * s0);
        ae[4] = f2bf(t1); ae[5] = f2bf(s1); ae[6] = f2bf(s1 * t1); ae[7] = f2bf(s1 * s1);
        ao[0] = f2bf(t2); ao[1] = f2bf(s2); ao[2] = f2bf(s2 * t2); ao[3] = f2bf(s2 * s2);
        ao[4] = f2bf(t3); ao[5] = f2bf(s3); ao[6] = f2bf(s3 * t3); ao[7] = f2bf(s3 * s3);
        acc0 = __builtin_amdgcn_mfma_f32_16x16x32_bf16(ae, be0, acc0, 0, 0, 0);
        acc1 = __builtin_amdgcn_mfma_f32_16x16x32_bf16(ae, be1, acc1, 0, 0, 0);
        acc0 = __builtin_amdgcn_mfma_f32_16x16x32_bf16(ao, bo0, acc0, 0, 0, 0);
        acc1 = __builtin_amdgcn_mfma_f32_16x16x32_bf16(ao, bo1, acc1, 0, 0, 0);
    }

    // ---- LayerNorm + ReLU + layer-2 ChebyKAN + sigmoid (one tile) ----
    // C layout: col = oh*16 + lr, row = g*4 + reg  (verified m89/m91)
    float* sw = reinterpret_cast<float*>(ws);   // scales reuse consumed tile
    {
        f32x4 a0 = acc0, a1 = acc1;
        float s[4], vs[4], z[4];
        #pragma unroll
        for (int r = 0; r < 4; ++r) s[r] = a0[r] + a1[r];
        #pragma unroll
        for (int m = 1; m <= 8; m <<= 1) {
            #pragma unroll
            for (int r = 0; r < 4; ++r) s[r] += __shfl_xor(s[r], m, 64);
        }
        #pragma unroll
        for (int r = 0; r < 4; ++r) {
            float mu = s[r] * (1.0f / 32.0f);
            float d0 = a0[r] - mu, d1 = a1[r] - mu;
            a0[r] = d0; a1[r] = d1;
            vs[r] = d0 * d0 + d1 * d1;
        }
        #pragma unroll
        for (int m = 1; m <= 8; m <<= 1) {
            #pragma unroll
            for (int r = 0; r < 4; ++r) vs[r] += __shfl_xor(vs[r], m, 64);
        }
        #pragma unroll
        for (int r = 0; r < 4; ++r) {
            float rs = rsqrtf(vs[r] * (1.0f / 32.0f) + 1e-5f);
            float h0 = fmaf(a0[r] * rs, gam0, bet0);
            float h1 = fmaf(a1[r] * rs, gam1, bet1);
            h0 = fmaxf(h0, 0.0f); h1 = fmaxf(h1, 0.0f);
            float t0 = tanh_fast(h0), t1 = tanh_fast(h1);
            float t02 = t0 * t0, t12 = t1 * t1;
            float zp = fmaf(e2a[0], t0, fmaf(e2a[1], t02,
                        fmaf(e2a[2], t02 * t0, e2a[3] * (t02 * t02))));
            zp += fmaf(e2b[0], t1, fmaf(e2b[1], t12,
                    fmaf(e2b[2], t12 * t1, e2b[3] * (t12 * t12))));
            z[r] = zp;
        }
        #pragma unroll
        for (int m = 1; m <= 8; m <<= 1) {
            #pragma unroll
            for (int r = 0; r < 4; ++r) z[r] += __shfl_xor(z[r], m, 64);
        }
        if (lr == 0) {
            #pragma unroll
            for (int r = 0; r < 4; ++r) {
                float attn = __builtin_amdgcn_rcpf(1.0f + __expf(-(z[r] + zb)));
                sw[g * 4 + r] = fmaf(alpha, attn, 1.0f);   // wave-local write
            }
        }
    }
    // no barrier: same-wave LDS write->read ordered via lgkmcnt

    // ---- sweep own 16 rows: out = PRV * (1 + alpha*attn) ----
    const float4* prv4 = reinterpret_cast<const float4*>(PRV) + rowbase;
    float4* out4 = reinterpret_cast<float4*>(out) + rowbase;
    #pragma unroll
    for (int it = 0; it < 8; ++it) {
        int fi = it * 64 + lane;
        float sc = sw[fi >> 5];
        float4 v = prv4[fi];
        v.x *= sc; v.y *= sc; v.z *= sc; v.w *= sc;
        out4[fi] = v;
    }
}

extern "C" void kernel_launch(void* const* d_in, const int* in_sizes, int n_in,
                              void* d_out, int out_size, void* d_ws, size_t ws_size,
                              hipStream_t stream) {
    const float* PRV    = (const float*)d_in[0];
    const float* PR     = (const float*)d_in[1];
    const float* c1     = (const float*)d_in[2];
    const float* gamma  = (const float*)d_in[3];
    const float* beta   = (const float*)d_in[4];
    const float* c2     = (const float*)d_in[5];
    const float* alphap = (const float*)d_in[6];
    float* out = (float*)d_out;

    unsigned short* Bpack = (unsigned short*)d_ws;            // 32 KB bf16 frags
    float* wsf   = (float*)((char*)d_ws + 32768);
    float* bias1 = wsf;          // 32
    float* E2    = wsf + 32;     // 128 (32 x float4)
    float* bias2 = wsf + 160;    // 1

    const int N = in_sizes[0] / C_DIM;

    hipLaunchKernelGGL(prep_kernel, dim3(64), dim3(256), 0, stream,
                       c1, c2, Bpack, bias1, E2, bias2);
    hipLaunchKernelGGL(fused_kernel, dim3(N / 128), dim3(512), 0, stream,
                       PRV, PR, Bpack, bias1, E2, bias2, gamma, beta, alphap, out);
}